// Round 4
// baseline (318.775 us; speedup 1.0000x reference)
//
#include <hip/hip_runtime.h>

#define NN     4096
#define MAXD   32      // degree cap (WS k=4 max degree ~12)
#define WUNR   8       // fully-unrolled ELL width; rows with c>8 take tail loop
#define TB     4       // tokens per round
#define ROUNDS 16      // rounds per block -> 64 tokens/block
#define BLK    1024

// Phase 1: build padded ELL (column-major [j][o]) of W*M, deterministically.
// One wave per output row o; ballot + prefix popcount -> indices sorted
// ascending -> fixed fp32 summation order. float2 {idx bitcast, w}; padding {0,0}.
__global__ __launch_bounds__(64) void build_ell_kernel(
    const float* __restrict__ weight, const float* __restrict__ mask,
    float2* __restrict__ ell, int* __restrict__ cnt) {
  const int o = blockIdx.x;
  const int lane = threadIdx.x;
  if (lane < MAXD) {
    float2 z; z.x = __uint_as_float(0u); z.y = 0.0f;
    ell[(size_t)lane * NN + o] = z;
  }
  __syncthreads();
  const float* mrow = mask + (size_t)o * NN;
  const float* wrow = weight + (size_t)o * NN;
  int count = 0;
  for (int base = 0; base < NN; base += 64) {
    const float m = mrow[base + lane];
    const bool nz = (m != 0.0f);
    const unsigned long long bal = __ballot(nz);
    if (nz) {
      const int pos = count + __popcll(bal & ((1ull << lane) - 1ull));
      if (pos < MAXD) {
        float2 e;
        e.x = __uint_as_float((unsigned)(base + lane));
        e.y = wrow[base + lane] * m;   // m == 1.0 exactly (exec-masked load: sparse W traffic)
        ell[(size_t)pos * NN + o] = e;
      }
    }
    count += __popcll(bal);
  }
  if (lane == 0) cnt[o] = (count < MAXD) ? count : MAXD;
}

// Phase 2: persistent double-buffered SpMM. One block per CU; each block owns
// 64 tokens processed as 16 rounds of 4. Per round: prefetch next 4 token rows
// into regs (overlaps with compute), gather-compute from xs[cur] (b128 = all 4
// tokens per ELL index), coalesced stores, ds_write regs -> xs[nxt], 1 barrier.
__global__ __launch_bounds__(BLK, 4) void ws_spmm_kernel(
    const float* __restrict__ x, const float* __restrict__ bias,
    const float2* __restrict__ ell, const int* __restrict__ cnt,
    float* __restrict__ out) {
  __shared__ float4 xs[2][NN];                       // 2 x 64 KiB
  const int tid = threadIdx.x;
  const size_t tok0 = (size_t)blockIdx.x * (TB * ROUNDS);

  // Hoist this thread's 4 output rows of ELL + cnt + bias (reused all rounds).
  float2 e[4][WUNR];
  int   cn[4];
  float bs[4];
#pragma unroll
  for (int q = 0; q < 4; ++q) {
    const int o = q * BLK + tid;
    cn[q] = cnt[o];
    bs[q] = bias[o];
#pragma unroll
    for (int j = 0; j < WUNR; ++j)
      e[q][j] = ell[(size_t)j * NN + o];
  }

  // Stage round 0.
  {
    const float* __restrict__ xb = x + tok0 * NN;
#pragma unroll
    for (int i = 0; i < NN / BLK; ++i) {
      const int c2 = tid + i * BLK;
      float4 v;
      v.x = xb[0 * NN + c2];
      v.y = xb[1 * NN + c2];
      v.z = xb[2 * NN + c2];
      v.w = xb[3 * NN + c2];
      xs[0][c2] = v;
    }
  }
  __syncthreads();

  for (int it = 0; it < ROUNDS; ++it) {
    const int cur = it & 1;

    // Prefetch next round's 4 token rows into registers (latency hides under compute).
    float xr[TB][NN / BLK];
    if (it + 1 < ROUNDS) {
      const float* __restrict__ xb = x + (tok0 + (size_t)(it + 1) * TB) * NN;
#pragma unroll
      for (int i = 0; i < NN / BLK; ++i) {
        const int c2 = tid + i * BLK;
#pragma unroll
        for (int t = 0; t < TB; ++t)
          xr[t][i] = xb[t * NN + c2];
      }
    }

    // Compute current round.
    const size_t t0 = tok0 + (size_t)it * TB;
#pragma unroll
    for (int q = 0; q < 4; ++q) {
      const int o = q * BLK + tid;
      float a0 = 0.f, a1 = 0.f, a2 = 0.f, a3 = 0.f;
#pragma unroll
      for (int j = 0; j < WUNR; ++j) {
        const unsigned ix = __float_as_uint(e[q][j].x);
        const float w = e[q][j].y;
        const float4 xv = xs[cur][ix];               // ds_read_b128: 4 tokens
        a0 = fmaf(xv.x, w, a0);
        a1 = fmaf(xv.y, w, a1);
        a2 = fmaf(xv.z, w, a2);
        a3 = fmaf(xv.w, w, a3);
      }
      for (int j = WUNR; j < cn[q]; ++j) {           // rare tail (degree > 8)
        const float2 et = ell[(size_t)j * NN + o];
        const unsigned ix = __float_as_uint(et.x);
        const float w = et.y;
        const float4 xv = xs[cur][ix];
        a0 = fmaf(xv.x, w, a0);
        a1 = fmaf(xv.y, w, a1);
        a2 = fmaf(xv.z, w, a2);
        a3 = fmaf(xv.w, w, a3);
      }
      float* op = out + t0 * NN + o;
      op[0]      = a0 + bs[q];
      op[NN]     = a1 + bs[q];
      op[2 * NN] = a2 + bs[q];
      op[3 * NN] = a3 + bs[q];
    }

    // Write prefetched regs into the other buffer.
    if (it + 1 < ROUNDS) {
      const int nxt = cur ^ 1;
#pragma unroll
      for (int i = 0; i < NN / BLK; ++i) {
        const int c2 = tid + i * BLK;
        xs[nxt][c2] = make_float4(xr[0][i], xr[1][i], xr[2][i], xr[3][i]);
      }
    }
    __syncthreads();
  }
}

extern "C" void kernel_launch(void* const* d_in, const int* in_sizes, int n_in,
                              void* d_out, int out_size, void* d_ws, size_t ws_size,
                              hipStream_t stream) {
  const float* x      = (const float*)d_in[0];
  const float* weight = (const float*)d_in[1];
  const float* bias   = (const float*)d_in[2];
  const float* mask   = (const float*)d_in[3];
  float* out = (float*)d_out;

  char* ws = (char*)d_ws;
  float2* ell = (float2*)ws;                                     // 1 MiB
  int*    cnt = (int*)(ws + (size_t)MAXD * NN * sizeof(float2)); // 16 KiB

  const int tokens = in_sizes[0] / NN;               // 16384

  build_ell_kernel<<<NN, 64, 0, stream>>>(weight, mask, ell, cnt);
  ws_spmm_kernel<<<tokens / (TB * ROUNDS), BLK, 0, stream>>>(x, bias, ell, cnt, out);
}

// Round 5
// 203.551 us; speedup vs baseline: 1.5661x; 1.5661x over previous
//
#include <hip/hip_runtime.h>

#define NN     4096
#define MAXD   32      // degree cap (WS k=4 max degree ~12)
#define WUNR   8       // fully-unrolled ELL width; rows with c>8 take tail loop
#define TB     4       // tokens per round
#define ROUNDS 16      // rounds per block -> 64 tokens/block
#define BLK    1024

// Phase 1: build padded ELL (column-major [j][o]) of W*M, deterministically.
// One wave per output row o; ballot + prefix popcount -> indices sorted
// ascending -> fixed fp32 summation order. float2 {idx bitcast, w}; padding {0,0}.
__global__ __launch_bounds__(64) void build_ell_kernel(
    const float* __restrict__ weight, const float* __restrict__ mask,
    float2* __restrict__ ell, int* __restrict__ cnt) {
  const int o = blockIdx.x;
  const int lane = threadIdx.x;
  if (lane < MAXD) {
    float2 z; z.x = __uint_as_float(0u); z.y = 0.0f;
    ell[(size_t)lane * NN + o] = z;
  }
  __syncthreads();
  const float* mrow = mask + (size_t)o * NN;
  const float* wrow = weight + (size_t)o * NN;
  int count = 0;
  for (int base = 0; base < NN; base += 64) {
    const float m = mrow[base + lane];
    const bool nz = (m != 0.0f);
    const unsigned long long bal = __ballot(nz);
    if (nz) {
      const int pos = count + __popcll(bal & ((1ull << lane) - 1ull));
      if (pos < MAXD) {
        float2 e;
        e.x = __uint_as_float((unsigned)(base + lane));
        e.y = wrow[base + lane] * m;   // m == 1.0 exactly
        ell[(size_t)pos * NN + o] = e;
      }
    }
    count += __popcll(bal);
  }
  if (lane == 0) cnt[o] = (count < MAXD) ? count : MAXD;
}

// Phase 2: persistent double-buffered SpMM, register-budget-safe (<64 VGPR).
// Per round: issue next round's 16 coalesced x loads into regs (HBM latency
// hides under compute), compute 4 output-quarters from xs[cur] (ds_read_b128
// = 4 tokens per ELL index; ELL entries re-loaded from L2 each round — cheap,
// 1 MiB L2-resident), store, ds_write prefetch -> xs[cur^1], one barrier.
__global__ __launch_bounds__(BLK, 4) void ws_spmm_kernel(
    const float* __restrict__ x, const float* __restrict__ bias,
    const float2* __restrict__ ell, const int* __restrict__ cnt,
    float* __restrict__ out) {
  __shared__ float4 xs[2][NN];                       // 2 x 64 KiB
  const int tid = threadIdx.x;
  const size_t tok0 = (size_t)blockIdx.x * (TB * ROUNDS);

  // Stage round 0.
  {
    const float* __restrict__ xb = x + tok0 * NN;
#pragma unroll
    for (int i = 0; i < NN / BLK; ++i) {
      const int c2 = tid + i * BLK;
      float4 v;
      v.x = xb[0 * NN + c2];
      v.y = xb[1 * NN + c2];
      v.z = xb[2 * NN + c2];
      v.w = xb[3 * NN + c2];
      xs[0][c2] = v;
    }
  }
  __syncthreads();

  for (int it = 0; it < ROUNDS; ++it) {
    const int cur = it & 1;

    // Prefetch next round's 4 token rows into registers.
    float xr[TB][NN / BLK];
    if (it + 1 < ROUNDS) {
      const float* __restrict__ xb = x + (tok0 + (size_t)(it + 1) * TB) * NN;
#pragma unroll
      for (int i = 0; i < NN / BLK; ++i) {
        const int c2 = tid + i * BLK;
#pragma unroll
        for (int t = 0; t < TB; ++t)
          xr[t][i] = xb[t * NN + c2];
      }
    }

    // Compute current round. q-loop NOT unrolled: keeps live regs ~16 (e) + 4 (acc).
    const size_t t0 = tok0 + (size_t)it * TB;
#pragma unroll 1
    for (int q = 0; q < NN / BLK; ++q) {
      const int o = q * BLK + tid;
      const int c = cnt[o];

      float2 e[WUNR];
#pragma unroll
      for (int j = 0; j < WUNR; ++j)
        e[j] = ell[(size_t)j * NN + o];              // coalesced dwordx2, L2-hit

      float a0 = 0.f, a1 = 0.f, a2 = 0.f, a3 = 0.f;
#pragma unroll
      for (int j = 0; j < WUNR; ++j) {
        const unsigned ix = __float_as_uint(e[j].x);
        const float w = e[j].y;
        const float4 xv = xs[cur][ix];               // ds_read_b128: 4 tokens
        a0 = fmaf(xv.x, w, a0);
        a1 = fmaf(xv.y, w, a1);
        a2 = fmaf(xv.z, w, a2);
        a3 = fmaf(xv.w, w, a3);
      }
      for (int j = WUNR; j < c; ++j) {               // rare tail (degree > 8)
        const float2 et = ell[(size_t)j * NN + o];
        const unsigned ix = __float_as_uint(et.x);
        const float w = et.y;
        const float4 xv = xs[cur][ix];
        a0 = fmaf(xv.x, w, a0);
        a1 = fmaf(xv.y, w, a1);
        a2 = fmaf(xv.z, w, a2);
        a3 = fmaf(xv.w, w, a3);
      }

      const float b = bias[o];
      float* op = out + t0 * NN + o;
      op[0]      = a0 + b;
      op[NN]     = a1 + b;
      op[2 * NN] = a2 + b;
      op[3 * NN] = a3 + b;
    }

    // Write prefetched regs into the other buffer; single barrier per round.
    if (it + 1 < ROUNDS) {
      const int nxt = cur ^ 1;
#pragma unroll
      for (int i = 0; i < NN / BLK; ++i) {
        const int c2 = tid + i * BLK;
        xs[nxt][c2] = make_float4(xr[0][i], xr[1][i], xr[2][i], xr[3][i]);
      }
    }
    __syncthreads();
  }
}

extern "C" void kernel_launch(void* const* d_in, const int* in_sizes, int n_in,
                              void* d_out, int out_size, void* d_ws, size_t ws_size,
                              hipStream_t stream) {
  const float* x      = (const float*)d_in[0];
  const float* weight = (const float*)d_in[1];
  const float* bias   = (const float*)d_in[2];
  const float* mask   = (const float*)d_in[3];
  float* out = (float*)d_out;

  char* ws = (char*)d_ws;
  float2* ell = (float2*)ws;                                     // 1 MiB
  int*    cnt = (int*)(ws + (size_t)MAXD * NN * sizeof(float2)); // 16 KiB

  const int tokens = in_sizes[0] / NN;               // 16384

  build_ell_kernel<<<NN, 64, 0, stream>>>(weight, mask, ell, cnt);
  ws_spmm_kernel<<<tokens / (TB * ROUNDS), BLK, 0, stream>>>(x, bias, ell, cnt, out);
}